// Round 5
// baseline (399.673 us; speedup 1.0000x reference)
//
#include <hip/hip_runtime.h>

typedef float f32x4 __attribute__((ext_vector_type(4)));
typedef __bf16 bf16x8 __attribute__((ext_vector_type(8)));

typedef __attribute__((address_space(3))) unsigned char lds_u8;
typedef __attribute__((address_space(1))) const unsigned char g_u8c;

__device__ __forceinline__ unsigned short f2bf(float f) {
  unsigned int u = __float_as_uint(f);
  u += 0x7FFFu + ((u >> 16) & 1u);   // round-to-nearest-even
  return (unsigned short)(u >> 16);
}
__device__ __forceinline__ unsigned int pk2(float a, float b) {
  return (unsigned int)f2bf(a) | ((unsigned int)f2bf(b) << 16);
}
__device__ __forceinline__ void gload16(const void* g, void* l) {
  __builtin_amdgcn_global_load_lds((g_u8c*)g, (lds_u8*)l, 16, 0, 0);
}

// ---- Kernel 0: weights -> bf16, fragment-contiguous layout + bias sum ----
// b-fragment for (kt,ct) is 1KB contiguous: wt[(kt*8+ct)*512 + lane*8 + j],
// lane=lg*16+l15 maps to (n=ct*16+l15, k=kt*32+lg*8+j).
__global__ void k_prep(const float* __restrict__ Ws, const float* __restrict__ Wn,
                       const float* __restrict__ bs, const float* __restrict__ bn,
                       unsigned short* __restrict__ wt, float* __restrict__ bias) {
  int idx = blockIdx.x * 256 + threadIdx.x;   // 0..32767
  int n = idx >> 8, k = idx & 255;
  float v = (k < 128) ? Ws[k * 128 + n] : Wn[(k - 128) * 128 + n];
  int ct = n >> 4, l15 = n & 15, kt = k >> 5, lg = (k >> 3) & 3, j = k & 7;
  wt[(((kt << 3) | ct) << 9) + (((lg << 4) | l15) << 3) + j] = f2bf(v);
  if (idx < 128) bias[idx] = bs[idx] + bn[idx];
}

// ---- Fused: 8-tile pipelined waves, double-buffered src LDS, counted vmcnt ----
// Wave owns rows [Wbase, Wbase+128): scan state carries across its 8 tiles.
__global__ __launch_bounds__(256, 2) void k_fused(
    const float* __restrict__ src, const float* __restrict__ dstf,
    const int* __restrict__ dst, const unsigned short* __restrict__ wt,
    const float* __restrict__ bias, float* __restrict__ out,
    float* __restrict__ dump, int E)
{
  __shared__ __align__(16) unsigned char sbuf[4][2][8192];   // 64 KB/WG -> 2 WG/CU
  const int lane = threadIdx.x & 63, wid = threadIdx.x >> 6;
  const int l15 = lane & 15, lg = lane >> 4;
  const long Wbase = ((long)blockIdx.x * 4 + wid) * 128;
  if (Wbase >= E) return;                      // no barriers anywhere -> safe
  const long emax = (long)E - 1;
  unsigned char* cur = sbuf[wid][0];
  unsigned char* nxt = sbuf[wid][1];

  // ---- stage tile 0 src (rule #21: linear LDS dest, inverse-swizzled source) ----
  #pragma unroll
  for (int i = 0; i < 8; ++i) {
    int r2 = i * 2 + (lane >> 5);
    long gr = Wbase + r2; if (gr > emax) gr = emax;
    int colb = ((lane & 31) << 4) ^ ((r2 & 7) << 5);
    gload16((const char*)src + gr * 512 + colb, cur + i * 1024);
  }

  // dst indices for tile 0
  long drow = Wbase + l15; if (drow > emax) drow = emax;
  int myd = dst[drow];

  float bcol[8];
  #pragma unroll
  for (int ct = 0; ct < 8; ++ct) bcol[ct] = bias[ct * 16 + l15];

  // ---- once-per-wave prologue: bucket start via ballot + base-sum ----
  int d0 = __shfl(myd, 0);
  long back = Wbase - 1 - lane;
  long backc = back < 0 ? 0 : back;
  int bd = dst[backc];
  unsigned long long m = __ballot((back >= 0) && (bd == d0));
  unsigned long long nm = ~m;
  int L = (nm == 0ull) ? 64 : __builtin_ctzll(nm);
  long s = Wbase - L;
  while (s > 0 && dst[s - 1] == d0) --s;       // bucket >64 deep: ~never
  float ax = 0.f, ay = 0.f;
  #pragma unroll 2
  for (long e = s; e < Wbase; ++e) {
    float2 v = *(const float2*)(src + e * 128 + lane * 2);
    ax += v.x; ay += v.y;
  }
  int pos = (int)(Wbase - s);
  int prevd = d0;

  asm volatile("s_waitcnt vmcnt(0)" ::: "memory");   // drain: known count = 0

  #pragma unroll 1
  for (int t = 0; t < 8; ++t) {
    const long e0 = Wbase + t * 16;

    // ---- scan tile t: src from cur (swz<<5), h bf16 overlay (swz<<4) ----
    #pragma unroll
    for (int r = 0; r < 16; ++r) {
      int d = __shfl(myd, r);
      if (d != prevd) { ax = 0.f; ay = 0.f; pos = 0; prevd = d; }
      float2 v = *(const float2*)(cur + r * 512 + ((lane * 8) ^ ((r & 7) << 5)));
      ax += v.x; ay += v.y;
      float inv = __builtin_amdgcn_rcpf((float)(pos + 1));
      *(unsigned int*)(cur + r * 512 + ((lane * 4) ^ ((r & 7) << 4))) = pk2(ax * inv, ay * inv);
      ++pos;
    }

    // ---- dstf fragments (plain loads; issued before stage group -> older) ----
    long arow = e0 + l15; if (arow > emax) arow = emax;
    const float* ap = dstf + arow * 128 + lg * 8;
    float4 af[8];
    #pragma unroll
    for (int kt = 0; kt < 4; ++kt) {
      af[kt * 2]     = *(const float4*)(ap + kt * 32);
      af[kt * 2 + 1] = *(const float4*)(ap + kt * 32 + 4);
    }

    // ---- MFMA: 16 rows x 128 cols, K=256 ----
    f32x4 acc[8];
    #pragma unroll
    for (int ct = 0; ct < 8; ++ct) acc[ct] = (f32x4){0.f, 0.f, 0.f, 0.f};
    #pragma unroll
    for (int kt = 0; kt < 8; ++kt) {
      bf16x8 a;
      if (kt < 4) {
        float4 x = af[kt * 2], y = af[kt * 2 + 1];
        union { unsigned int u[4]; bf16x8 v; } cv;
        cv.u[0] = pk2(x.x, x.y); cv.u[1] = pk2(x.z, x.w);
        cv.u[2] = pk2(y.x, y.y); cv.u[3] = pk2(y.z, y.w);
        a = cv.v;
      } else {
        a = *(const bf16x8*)(cur + l15 * 512 + ((((kt - 4) * 64) + lg * 16) ^ ((l15 & 7) << 4)));
      }
      bf16x8 b[8];
      #pragma unroll
      for (int ct = 0; ct < 8; ++ct)           // 1KB coalesced fragment (L2-hot)
        b[ct] = *(const bf16x8*)(wt + (((kt << 3) | ct) << 9) + (lane << 3));
      #pragma unroll
      for (int ct = 0; ct < 8; ++ct)
        acc[ct] = __builtin_amdgcn_mfma_f32_16x16x32_bf16(a, b[ct], acc[ct], 0, 0, 0);
    }

    // ---- stage tile t+1 + next dst idx (counted group) ----
    if (t < 7) {
      asm volatile("" ::: "memory");           // fence: stage stays after MFMA/h-reads
      #pragma unroll
      for (int i = 0; i < 8; ++i) {
        int r2 = i * 2 + (lane >> 5);
        long gr = e0 + 16 + r2; if (gr > emax) gr = emax;
        int colb = ((lane & 31) << 4) ^ ((r2 & 7) << 5);
        gload16((const char*)src + gr * 512 + colb, nxt + i * 1024);
      }
      long nd = e0 + 16 + l15; if (nd > emax) nd = emax;
      myd = dst[nd];
      asm volatile("" ::: "memory");           // fence: stores stay after stage
    }

    // ---- epilogue: always 32 stores (OOB rows -> dump) for uniform vmcnt ----
    #pragma unroll
    for (int i = 0; i < 4; ++i) {
      long row = e0 + lg * 4 + i;
      float* op = (row < E) ? (out + row * 128 + l15) : (dump + lane);
      #pragma unroll
      for (int ct = 0; ct < 8; ++ct) op[ct * 16] = acc[ct][i] + bcol[ct];
    }

    // ---- counted wait: 32 stores younger than stage group => stage landed ----
    if (t < 7) asm volatile("s_waitcnt vmcnt(32)" ::: "memory");

    unsigned char* tmp = cur; cur = nxt; nxt = tmp;
  }
}

extern "C" void kernel_launch(void* const* d_in, const int* in_sizes, int n_in,
                              void* d_out, int out_size, void* d_ws, size_t ws_size,
                              hipStream_t stream) {
  const float* src_feat = (const float*)d_in[0];
  const float* dst_feat = (const float*)d_in[1];
  const int*   dst      = (const int*)d_in[2];
  const float* W_self   = (const float*)d_in[3];
  const float* b_self   = (const float*)d_in[4];
  const float* W_neigh  = (const float*)d_in[5];
  const float* b_neigh  = (const float*)d_in[6];
  float* out = (float*)d_out;
  const int E = in_sizes[2];

  unsigned short* wt   = (unsigned short*)d_ws;            // 64KB repacked weights
  float*          bias = (float*)((char*)d_ws + 65536);    // 512B
  float*          dump = (float*)((char*)d_ws + 131072);   // OOB store sink (16KB)

  k_prep<<<128, 256, 0, stream>>>(W_self, W_neigh, b_self, b_neigh, wt, bias);

  int blocks = (E + 511) / 512;   // 4 waves/WG x 128 rows/wave
  k_fused<<<blocks, 256, 0, stream>>>(src_feat, dst_feat, dst, wt, bias, out, dump, E);
}

// Round 6
// 190.549 us; speedup vs baseline: 2.0975x; 2.0975x over previous
//
#include <hip/hip_runtime.h>

typedef float f32x4 __attribute__((ext_vector_type(4)));
typedef __bf16 bf16x8 __attribute__((ext_vector_type(8)));

typedef __attribute__((address_space(3))) unsigned char lds_u8;
typedef __attribute__((address_space(1))) const unsigned char g_u8c;

__device__ __forceinline__ unsigned short f2bf(float f) {
  unsigned int u = __float_as_uint(f);
  u += 0x7FFFu + ((u >> 16) & 1u);   // round-to-nearest-even
  return (unsigned short)(u >> 16);
}
__device__ __forceinline__ unsigned int pk2(float a, float b) {
  return (unsigned int)f2bf(a) | ((unsigned int)f2bf(b) << 16);
}
__device__ __forceinline__ void gload16(const void* g, void* l) {
  __builtin_amdgcn_global_load_lds((g_u8c*)g, (lds_u8*)l, 16, 0, 0);
}

// ---- Kernel 0: weights -> bf16, fragment-contiguous layout + bias sum ----
// b-fragment for (kt,ct) is 1KB contiguous: wt[(kt*8+ct)*512 + lane*8 + j],
// lane=lg*16+l15 maps to (n=ct*16+l15, k=kt*32+lg*8+j).
__global__ void k_prep(const float* __restrict__ Ws, const float* __restrict__ Wn,
                       const float* __restrict__ bs, const float* __restrict__ bn,
                       unsigned short* __restrict__ wt, float* __restrict__ bias) {
  int idx = blockIdx.x * 256 + threadIdx.x;   // 0..32767
  int n = idx >> 8, k = idx & 255;
  float v = (k < 128) ? Ws[k * 128 + n] : Wn[(k - 128) * 128 + n];
  int ct = n >> 4, l15 = n & 15, kt = k >> 5, lg = (k >> 3) & 3, j = k & 7;
  wt[(((kt << 3) | ct) << 9) + (((lg << 4) | l15) << 3) + j] = f2bf(v);
  if (idx < 128) bias[idx] = bs[idx] + bn[idx];
}

// ---- Fused: 2 independent waves per WG, 16 rows/wave, async LDS staging ----
// Round-4 dataflow exactly; WG packing doubled to lift the 8-WG/CU cap.
__global__ __launch_bounds__(128, 4) void k_fused(
    const float* __restrict__ src, const float* __restrict__ dstf,
    const int* __restrict__ dst, const unsigned short* __restrict__ wt,
    const float* __restrict__ bias, float* __restrict__ out, int E)
{
  // per-wave slab: [0,8192) = src f32 swizzled (h bf16 overlays bytes [0,256)
  // of each 512B row after consumption); [8192,16384) = dstf f32 swizzled.
  __shared__ __align__(16) unsigned char slab[2][16384];
  const int lane = threadIdx.x & 63, wid = threadIdx.x >> 6;
  const int l15 = lane & 15, lg = lane >> 4;

  // bijective XCD swizzle (m204): consecutive row-blocks share an XCD's L2
  const int nwg = gridDim.x, bid = blockIdx.x;
  const int q = nwg >> 3, r = nwg & 7;
  const int xcd = bid & 7, ix = bid >> 3;
  const int swb = (xcd < r ? xcd * (q + 1) : r * (q + 1) + (xcd - r) * q) + ix;

  const long e0 = ((long)swb * 2 + wid) * 16;
  if (e0 >= E) return;                         // no barriers anywhere -> safe
  const long emax = (long)E - 1;
  unsigned char* ssrc = slab[wid];
  unsigned char* sdst = slab[wid] + 8192;

  // ---- dst index loads first (feed ballot) ----
  long drow = e0 + l15; if (drow > emax) drow = emax;
  int myd = dst[drow];
  long back = e0 - 1 - lane;
  long backc = back < 0 ? 0 : back;
  int bd = dst[backc];

  // ---- async stage: 16 src rows then 16 dstf rows (1KB per issue) ----
  // phys[r*512 + (c ^ ((r&7)<<5))] = logical row r byte c (linear LDS dest,
  // inverse-swizzled global source).
  #pragma unroll
  for (int i = 0; i < 8; ++i) {
    int r2 = i * 2 + (lane >> 5);
    long gr = e0 + r2; if (gr > emax) gr = emax;
    int colb = ((lane & 31) << 4) ^ ((r2 & 7) << 5);
    gload16((const char*)src + gr * 512 + colb, ssrc + i * 1024);
  }
  #pragma unroll
  for (int i = 0; i < 8; ++i) {
    int r2 = i * 2 + (lane >> 5);
    long gr = e0 + r2; if (gr > emax) gr = emax;
    int colb = ((lane & 31) << 4) ^ ((r2 & 7) << 5);
    gload16((const char*)dstf + gr * 512 + colb, sdst + i * 1024);
  }

  // ---- bucket start via ballot (dst is L2/L3-hot: 2MB) ----
  int d0 = __shfl(myd, 0);
  unsigned long long m = __ballot((back >= 0) && (bd == d0));
  unsigned long long nm = ~m;
  int L = (nm == 0ull) ? 64 : __builtin_ctzll(nm);
  long s = e0 - L;
  while (s > 0 && dst[s - 1] == d0) --s;       // bucket >64 deep: ~never

  // ---- partial-bucket base sum from global (neighbor rows: L2/L3-hot) ----
  float ax = 0.f, ay = 0.f;
  for (long e = s; e < e0; ++e) {
    float2 v = *(const float2*)(src + e * 128 + lane * 2);
    ax += v.x; ay += v.y;
  }

  // src rows staged (dstf may still be in flight)
  asm volatile("s_waitcnt vmcnt(8)" ::: "memory");

  // ---- cummean scan: read src row r from LDS, write h row r (bf16) over it ----
  int pos = (int)(e0 - s);
  int prevd = d0;
  #pragma unroll
  for (int rr = 0; rr < 16; ++rr) {
    int d = __shfl(myd, rr);
    if (d != prevd) { ax = 0.f; ay = 0.f; pos = 0; prevd = d; }
    float2 v = *(const float2*)(ssrc + rr * 512 + ((lane * 8) ^ ((rr & 7) << 5)));
    ax += v.x; ay += v.y;
    float inv = __builtin_amdgcn_rcpf((float)(pos + 1));
    *(unsigned int*)(ssrc + rr * 512 + ((lane * 4) ^ ((rr & 7) << 4))) = pk2(ax * inv, ay * inv);
    ++pos;
  }

  asm volatile("s_waitcnt lgkmcnt(0)" ::: "memory");   // h writes landed
  asm volatile("s_waitcnt vmcnt(0)" ::: "memory");     // dstf staged

  // ---- MFMA: 16 rows x 128 cols, K=256 ----
  f32x4 acc[8];
  #pragma unroll
  for (int ct = 0; ct < 8; ++ct) acc[ct] = (f32x4){0.f, 0.f, 0.f, 0.f};
  float bcol[8];
  #pragma unroll
  for (int ct = 0; ct < 8; ++ct) bcol[ct] = bias[ct * 16 + l15];

  #pragma unroll
  for (int kt = 0; kt < 8; ++kt) {
    bf16x8 a;
    if (kt < 4) {                              // dst_feat f32 from LDS -> bf16
      const unsigned char* p = sdst + l15 * 512 + ((kt * 128 + lg * 32) ^ ((l15 & 7) << 5));
      float4 x = *(const float4*)p;
      float4 y = *(const float4*)(p + 16);
      union { unsigned int u[4]; bf16x8 v; } cv;
      cv.u[0] = pk2(x.x, x.y); cv.u[1] = pk2(x.z, x.w);
      cv.u[2] = pk2(y.x, y.y); cv.u[3] = pk2(y.z, y.w);
      a = cv.v;
    } else {                                   // h bf16 from LDS (overlaid in ssrc)
      a = *(const bf16x8*)(ssrc + l15 * 512 + ((((kt - 4) * 64) + lg * 16) ^ ((l15 & 7) << 4)));
    }
    bf16x8 b[8];
    #pragma unroll
    for (int ct = 0; ct < 8; ++ct)             // 1KB coalesced fragment (L2-hot)
      b[ct] = *(const bf16x8*)(wt + (((kt << 3) | ct) << 9) + (lane << 3));
    #pragma unroll
    for (int ct = 0; ct < 8; ++ct)
      acc[ct] = __builtin_amdgcn_mfma_f32_16x16x32_bf16(a, b[ct], acc[ct], 0, 0, 0);
  }

  // ---- epilogue: D layout col=lane&15, row=(lane>>4)*4+i ----
  #pragma unroll
  for (int i = 0; i < 4; ++i) {
    long row = e0 + lg * 4 + i;
    if (row < E) {
      float* op = out + row * 128 + l15;
      #pragma unroll
      for (int ct = 0; ct < 8; ++ct) op[ct * 16] = acc[ct][i] + bcol[ct];
    }
  }
}

extern "C" void kernel_launch(void* const* d_in, const int* in_sizes, int n_in,
                              void* d_out, int out_size, void* d_ws, size_t ws_size,
                              hipStream_t stream) {
  const float* src_feat = (const float*)d_in[0];
  const float* dst_feat = (const float*)d_in[1];
  const int*   dst      = (const int*)d_in[2];
  const float* W_self   = (const float*)d_in[3];
  const float* b_self   = (const float*)d_in[4];
  const float* W_neigh  = (const float*)d_in[5];
  const float* b_neigh  = (const float*)d_in[6];
  float* out = (float*)d_out;
  const int E = in_sizes[2];

  unsigned short* wt   = (unsigned short*)d_ws;           // 64KB repacked weights
  float*          bias = (float*)((char*)d_ws + 65536);   // 512B

  k_prep<<<128, 256, 0, stream>>>(W_self, W_neigh, b_self, b_neigh, wt, bias);

  int blocks = (E + 31) / 32;   // 2 waves/WG x 16 rows/wave
  k_fused<<<blocks, 128, 0, stream>>>(src_feat, dst_feat, dst, wt, bias, out, E);
}